// Round 5
// baseline (246.741 us; speedup 1.0000x reference)
//
#include <hip/hip_runtime.h>
#include <hip/hip_bf16.h>
#include <hip/hip_fp16.h>
#include <math.h>

#define NB 64
#define CC 512
#define LL 256

typedef __attribute__((ext_vector_type(4))) float floatx4;
typedef __attribute__((ext_vector_type(8))) short short8;

static __device__ __forceinline__ unsigned f2bf2(float x, float y) {
    __hip_bfloat162 h = __float22bfloat162_rn(make_float2(x, y));
    union { __hip_bfloat162 h; unsigned u; } c; c.h = h;
    return c.u;   // low 16 = x, high 16 = y
}
static __device__ __forceinline__ unsigned short f2h(float x) {
    __half h = __float2half_rn(x);
    union { __half h; unsigned short u; } c; c.h = h;
    return c.u;
}
static __device__ __forceinline__ float h2f(unsigned u) {
    union { unsigned short u; __half h; } c; c.u = (unsigned short)u;
    return __half2float(c.h);
}
// agent-scope relaxed loads: bypass local (possibly stale) cache; pair with the
// writers' release fence + counter RMW chain for cross-XCD visibility.
static __device__ __forceinline__ float ld_agent_f32(const float* p) {
    return __hip_atomic_load(p, __ATOMIC_RELAXED, __HIP_MEMORY_SCOPE_AGENT);
}
static __device__ __forceinline__ unsigned long long ld_agent_u64(const unsigned long long* p) {
    return __hip_atomic_load(p, __ATOMIC_RELAXED, __HIP_MEMORY_SCOPE_AGENT);
}

// decode linear t -> upper-tri (tI,tJ) of a u x u tile grid
static __device__ __forceinline__ bool decode_tile(int t, int u, int& tI, int& tJ) {
    if (t >= (u * (u + 1)) >> 1) return false;
    tI = 0;
    while (t >= u - tI) { t -= u - tI; ++tI; }
    tJ = tI + t;
    return true;
}

// ================= single fused kernel (fan-in, no grid sync, no spin) =================
// bx = (t*2+mat)*64 + n  =>  bx % 8 == n % 8 (XCD-clustered per batch).
// Tile phase: identical to the proven R2 dist (inline ballot prep, f32 staging,
// dbuf LDS, 4 MFMA/chunk/wave, D fp16 store, sum slot store).
// Fan-in: threadfence + bcnt[n] acq_rel RMW; the LAST tile block of batch n
// streams the batch's D tiles (agent loads), does Huber, writes hout[n], bumps
// gcnt; the 64th finisher sums hout[] -> out[0] (plain store, no zero-init).
__global__ __launch_bounds__(256) void mega_kernel(
    const float* __restrict__ S, const float* __restrict__ T,
    const int* __restrict__ targets,
    int* __restrict__ bcnt, int* __restrict__ gcnt, float* __restrict__ hout,
    float* __restrict__ sumS, float* __restrict__ sumT,
    unsigned short* __restrict__ Ds, unsigned short* __restrict__ Dt,
    float* __restrict__ out)
{
    const int bx = blockIdx.x;
    const int n = bx & (NB - 1);
    const int q = bx >> 6;
    const int mat = q & 1, t = q >> 1;
    const int tid = threadIdx.x;
    const int w = tid >> 6, lane = tid & 63;

    __shared__ __align__(16) unsigned short lds[2][2][64][40];  // 20 KB
    __shared__ float s_norm[2][64];
    __shared__ float red[4];
    __shared__ int s_idx[CC];
    __shared__ int s_cnt[8], s_off[8];
    __shared__ int s_np, s_flag;

    // ---- ballot counts (cheap; scatter deferred until we know we're active) ----
    const int* tg = targets + n * CC;
    const bool p0 = tg[tid] != 0;
    const bool p1 = tg[tid + 256] != 0;
    const unsigned long long m0 = __ballot(p0);
    const unsigned long long m1 = __ballot(p1);
    if (lane == 0) { s_cnt[w] = __popcll(m0); s_cnt[4 + w] = __popcll(m1); }
    __syncthreads();
    if (tid == 0) {
        int a = 0;
        for (int i = 0; i < 8; ++i) { s_off[i] = a; a += s_cnt[i]; }
        s_np = a;
    }
    __syncthreads();
    const int np = s_np;

    // ---- degenerate batch: the (t=0,mat=0) block signals a zero contribution ----
    if (np < 2) {
        if (t != 0 || mat != 0) return;
        if (tid == 0) {
            hout[n] = 0.0f;
            __threadfence();
            s_flag = __hip_atomic_fetch_add(gcnt, 1, __ATOMIC_ACQ_REL, __HIP_MEMORY_SCOPE_AGENT);
        }
        __syncthreads();
        if (s_flag == NB - 1) {
            if (tid < 64) {
                float v = ld_agent_f32(hout + tid);
                #pragma unroll
                for (int o = 32; o; o >>= 1) v += __shfl_down(v, o);
                if (tid == 0) out[0] = v;
            }
        }
        return;
    }

    const int u = (np + 63) >> 6;
    const int ntiles = (u * (u + 1)) >> 1;
    if (t >= ntiles) return;

    // ---- scatter compaction indices (only active blocks pay this) ----
    const unsigned long long below = (1ull << lane) - 1ull;
    if (p0) s_idx[s_off[w] + __popcll(m0 & below)] = tid;
    if (p1) s_idx[s_off[4 + w] + __popcll(m1 & below)] = tid + 256;
    __syncthreads();

    int tI, tJ;
    decode_tile(t, u, tI, tJ);
    const bool diag = (tI == tJ);

    const float* P = (mat ? T : S) + (size_t)n * CC * LL;
    unsigned short* Dout = (mat ? Dt : Ds) + (((size_t)t * NB + n) << 12);

    // staging: logical rows 0..127 = A rows 0..63 then B rows 64..127 (diag: A only)
    const int srow = w * 32 + (lane >> 1);
    const int half = lane & 1;                 // which 64 B half of the row's 128 B chunk
    const bool stager = diag ? (srow < 64) : true;
    const int ab = srow >> 6, rloc = srow & 63;
    const int gk = (ab ? tJ : tI) * 64 + rloc;
    const int row = s_idx[(gk < np) ? gk : 0];
    const char* rp = (const char*)P + (size_t)row * (LL * 4) + half * 64;

    float4 pre[4];
    float nsum = 0.0f;
    if (stager) {
        #pragma unroll
        for (int i = 0; i < 4; ++i) pre[i] = *(const float4*)(rp + i * 16);
    }

    const int m16 = lane & 15, quad = lane >> 4;
    const int bufB = diag ? 0 : 1;
    const int wrow = w * 16;

    floatx4 acc[4];
    #pragma unroll
    for (int c = 0; c < 4; ++c) { acc[c][0] = 0; acc[c][1] = 0; acc[c][2] = 0; acc[c][3] = 0; }

    for (int kk = 0; kk < 8; ++kk) {
        const int pb = kk & 1;
        if (stager) {
            // safe: chunk kk-2's reads of buf pb drained at barrier kk-1 (lgkmcnt)
            #pragma unroll
            for (int i = 0; i < 4; ++i)
                nsum += pre[i].x * pre[i].x + pre[i].y * pre[i].y +
                        pre[i].z * pre[i].z + pre[i].w * pre[i].w;
            unsigned short* dst = &lds[ab][pb][rloc][half * 16];
            *(uint2*)(dst + 0)  = make_uint2(f2bf2(pre[0].x, pre[0].y), f2bf2(pre[0].z, pre[0].w));
            *(uint2*)(dst + 4)  = make_uint2(f2bf2(pre[1].x, pre[1].y), f2bf2(pre[1].z, pre[1].w));
            *(uint2*)(dst + 8)  = make_uint2(f2bf2(pre[2].x, pre[2].y), f2bf2(pre[2].z, pre[2].w));
            *(uint2*)(dst + 12) = make_uint2(f2bf2(pre[3].x, pre[3].y), f2bf2(pre[3].z, pre[3].w));
        }
        __syncthreads();   // single barrier per chunk
        if (stager && kk < 7) {                // prefetch next chunk during MFMA
            #pragma unroll
            for (int i = 0; i < 4; ++i)
                pre[i] = *(const float4*)(rp + (kk + 1) * 128 + i * 16);
        }
        const short8 a = *(const short8*)&lds[0][pb][wrow + m16][quad * 8];
        #pragma unroll
        for (int c = 0; c < 4; ++c) {
            const short8 b = *(const short8*)&lds[bufB][pb][c * 16 + m16][quad * 8];
            acc[c] = __builtin_amdgcn_mfma_f32_16x16x32_bf16(a, b, acc[c], 0, 0, 0);
        }
    }

    // ---- inline norms: 2 lanes share each staged row ----
    if (stager) {
        const float v = nsum + __shfl_xor(nsum, 1);
        if (half == 0) s_norm[ab][rloc] = v;
    }
    __syncthreads();

    // ---- distances; C/D layout: col=lane&15, row=quad*4+reg ----
    float l0 = 0.0f;
    #pragma unroll
    for (int c = 0; c < 4; ++c) {
        const int colL = c * 16 + m16;
        const int gj = tJ * 64 + colL;
        const float nB = s_norm[bufB][colL];
        #pragma unroll
        for (int r = 0; r < 4; ++r) {
            const int rowL = wrow + quad * 4 + r;
            const int gi = tI * 64 + rowL;
            const float d = sqrtf(fmaxf(s_norm[0][rowL] + nB - 2.0f * acc[c][r], 1e-12f));
            if (gi < np && gj < np && gi != gj) l0 += d;
            Dout[rowL * 64 + colL] = f2h(d);
        }
    }

    #pragma unroll
    for (int o = 32; o; o >>= 1) l0 += __shfl_down(l0, o);
    if (lane == 0) red[w] = l0;
    __syncthreads();   // also drains all D stores into L2 (vmcnt(0) before s_barrier)
    if (tid == 0) {
        const float wgt = diag ? 1.0f : 2.0f;  // off-diag tiles mirror-counted
        (mat ? sumT : sumS)[t * NB + n] = wgt * (red[0] + red[1] + red[2] + red[3]);
        __threadfence();   // agent release: D tile + sum slot visible device-wide
        s_flag = __hip_atomic_fetch_add(&bcnt[n], 1, __ATOMIC_ACQ_REL, __HIP_MEMORY_SCOPE_AGENT);
    }
    __syncthreads();
    if (s_flag != 2 * ntiles - 1) return;

    // ======== batch finisher: Huber over all of batch n's tiles ========
    // means (each wave redundantly; ntiles <= 36 <= 64 lanes)
    float a = 0.0f, b = 0.0f;
    if (lane < ntiles) {
        a = ld_agent_f32(&sumS[lane * NB + n]);
        b = ld_agent_f32(&sumT[lane * NB + n]);
    }
    #pragma unroll
    for (int o = 32; o; o >>= 1) { a += __shfl_down(a, o); b += __shfl_down(b, o); }
    a = __shfl(a, 0); b = __shfl(b, 0);

    const float cnt = (float)np * (float)(np - 1);
    const float inv_ms = cnt / a;
    const float inv_mt = cnt / b;

    float h = 0.0f;
    for (int tt = 0; tt < ntiles; ++tt) {
        int eI, eJ; decode_tile(tt, u, eI, eJ);
        const float wgt = (eI == eJ) ? 1.0f : 2.0f;
        const size_t slot = ((size_t)tt * NB + n) << 12;
        const unsigned long long* ps = (const unsigned long long*)(Ds + slot);  // 1024 u64
        const unsigned long long* pt = (const unsigned long long*)(Dt + slot);
        float hl = 0.0f;
        #pragma unroll
        for (int it = 0; it < 4; ++it) {
            const int g = it * 256 + tid;          // u64 group; 4 entries each
            const unsigned long long ua = ld_agent_u64(ps + g);
            const unsigned long long ub = ld_agent_u64(pt + g);
            const int e0 = g * 4;
            #pragma unroll
            for (int k = 0; k < 4; ++k) {
                const int e = e0 + k;
                const int gi = eI * 64 + (e >> 6);
                const int gj = eJ * 64 + (e & 63);
                if (gi < np && gj < np && gi != gj) {
                    const float ds = h2f((unsigned)((ua >> (16 * k)) & 0xffffu));
                    const float dt = h2f((unsigned)((ub >> (16 * k)) & 0xffffu));
                    const float diff = ds * inv_ms - dt * inv_mt;
                    const float ad = fabsf(diff);
                    hl += (ad < 1.0f) ? 0.5f * diff * diff : ad - 0.5f;
                }
            }
        }
        h += wgt * hl;
    }

    #pragma unroll
    for (int o = 32; o; o >>= 1) h += __shfl_down(h, o);
    if (lane == 0) red[w] = h;
    __syncthreads();
    if (tid == 0) {
        hout[n] = (red[0] + red[1] + red[2] + red[3]) / (float)np;
        __threadfence();
        s_flag = __hip_atomic_fetch_add(gcnt, 1, __ATOMIC_ACQ_REL, __HIP_MEMORY_SCOPE_AGENT);
    }
    __syncthreads();
    if (s_flag == NB - 1) {   // globally last batch: sum per-batch results -> out
        if (tid < 64) {
            float v = ld_agent_f32(hout + tid);
            #pragma unroll
            for (int o = 32; o; o >>= 1) v += __shfl_down(v, o);
            if (tid == 0) out[0] = v;
        }
    }
}

extern "C" void kernel_launch(void* const* d_in, const int* in_sizes, int n_in,
                              void* d_out, int out_size, void* d_ws, size_t ws_size,
                              hipStream_t stream) {
    const float* S = (const float*)d_in[0];
    const float* T = (const float*)d_in[1];
    const int* targets = (const int*)d_in[2];
    float* out = (float*)d_out;

    char* p = (char*)d_ws;
    int* bcnt = (int*)p;                          // 64 ints
    int* gcnt = (int*)(p + 256);                  // 1 int
    float* hout = (float*)(p + 512);              // 64 floats
    float* sumS = (float*)(p + 768);              // 36*64 slots
    float* sumT = sumS + 36 * NB;
    p += 768 + (size_t)2 * 36 * NB * 4;
    p = (char*)(((size_t)p + 255) & ~(size_t)255);
    unsigned short* Ds = (unsigned short*)p;  p += (size_t)36 * NB * 4096 * 2;  // 18.9 MB
    unsigned short* Dt = (unsigned short*)p;                                     // 18.9 MB

    hipMemsetAsync(bcnt, 0, 512, stream);         // zero bcnt + gcnt (capture-safe stream op)
    mega_kernel<<<72 * NB, 256, 0, stream>>>(S, T, targets, bcnt, gcnt, hout,
                                             sumS, sumT, Ds, Dt, out);
}

// Round 7
// 241.203 us; speedup vs baseline: 1.0230x; 1.0230x over previous
//
#include <hip/hip_runtime.h>
#include <hip/hip_bf16.h>
#include <hip/hip_fp16.h>
#include <math.h>

#define NB 64
#define CC 512
#define LL 256

typedef __attribute__((ext_vector_type(4))) float floatx4;
typedef __attribute__((ext_vector_type(8))) short short8;

static __device__ __forceinline__ unsigned f2bf2(float x, float y) {
    __hip_bfloat162 h = __float22bfloat162_rn(make_float2(x, y));
    union { __hip_bfloat162 h; unsigned u; } c; c.h = h;
    return c.u;   // low 16 = x, high 16 = y
}
static __device__ __forceinline__ unsigned short f2h(float x) {
    __half h = __float2half_rn(x);
    union { __half h; unsigned short u; } c; c.h = h;
    return c.u;
}
static __device__ __forceinline__ float h2f(unsigned u) {
    union { unsigned short u; __half h; } c; c.u = (unsigned short)u;
    return __half2float(c.h);
}
static __device__ __forceinline__ float ld_agent_f32(const float* p) {
    return __hip_atomic_load(p, __ATOMIC_RELAXED, __HIP_MEMORY_SCOPE_AGENT);
}

// decode linear t -> upper-tri (tI,tJ) of a u x u tile grid
static __device__ __forceinline__ bool decode_tile(int t, int u, int& tI, int& tJ) {
    if (t >= (u * (u + 1)) >> 1) return false;
    tI = 0;
    while (t >= u - tI) { t -= u - tI; ++tI; }
    tJ = tI + t;
    return true;
}

// ================= single fused kernel (fan-in, no spin — R5 skeleton) =================
// bx = (t*2+mat)*64 + n  =>  bx % 8 == n % 8 (XCD-clustered per batch).
// Tile phase: proven R2 dist (inline ballot prep, f32 staging, dbuf LDS,
// 4 MFMA/chunk/wave, D fp16 store, sum slot store).
// Fan-in: threadfence (agent release) + bcnt[n] ACQ_REL RMW. The RMW's acquire
// invalidates local caches, so the LAST tile block of batch n streams the
// batch's D tiles with PLAIN vectorized loads (pipelined — this is the fix for
// R5's 150us serialized-atomic-load tail), does Huber, writes hout[n], bumps
// gcnt; the 64th batch-finisher sums hout[] -> out[0] (plain store, no zero-init).
__global__ __launch_bounds__(256) void mega_kernel(
    const float* __restrict__ S, const float* __restrict__ T,
    const int* __restrict__ targets,
    int* __restrict__ bcnt, int* __restrict__ gcnt, float* __restrict__ hout,
    float* __restrict__ sumS, float* __restrict__ sumT,
    unsigned short* __restrict__ Ds, unsigned short* __restrict__ Dt,
    float* __restrict__ out)
{
    const int bx = blockIdx.x;
    const int n = bx & (NB - 1);
    const int q = bx >> 6;
    const int mat = q & 1, t = q >> 1;
    const int tid = threadIdx.x;
    const int w = tid >> 6, lane = tid & 63;

    __shared__ __align__(16) unsigned short lds[2][2][64][40];  // 20 KB
    __shared__ float s_norm[2][64];
    __shared__ float red[4];
    __shared__ int s_idx[CC];
    __shared__ int s_cnt[8], s_off[8];
    __shared__ int s_np, s_flag;

    // ---- ballot counts ----
    const int* tg = targets + n * CC;
    const bool p0 = tg[tid] != 0;
    const bool p1 = tg[tid + 256] != 0;
    const unsigned long long m0 = __ballot(p0);
    const unsigned long long m1 = __ballot(p1);
    if (lane == 0) { s_cnt[w] = __popcll(m0); s_cnt[4 + w] = __popcll(m1); }
    __syncthreads();
    if (tid == 0) {
        int a = 0;
        for (int i = 0; i < 8; ++i) { s_off[i] = a; a += s_cnt[i]; }
        s_np = a;
    }
    __syncthreads();
    const int np = s_np;

    // ---- degenerate batch: the (t=0,mat=0) block signals a zero contribution ----
    if (np < 2) {
        if (t != 0 || mat != 0) return;
        if (tid == 0) {
            hout[n] = 0.0f;
            __threadfence();
            s_flag = __hip_atomic_fetch_add(gcnt, 1, __ATOMIC_ACQ_REL, __HIP_MEMORY_SCOPE_AGENT);
        }
        __syncthreads();
        if (s_flag == NB - 1) {
            if (tid < 64) {
                float v = ld_agent_f32(hout + tid);
                #pragma unroll
                for (int o = 32; o; o >>= 1) v += __shfl_down(v, o);
                if (tid == 0) out[0] = v;
            }
        }
        return;
    }

    const int u = (np + 63) >> 6;
    const int ntiles = (u * (u + 1)) >> 1;
    if (t >= ntiles) return;

    // ---- scatter compaction indices (only active blocks pay this) ----
    const unsigned long long below = (1ull << lane) - 1ull;
    if (p0) s_idx[s_off[w] + __popcll(m0 & below)] = tid;
    if (p1) s_idx[s_off[4 + w] + __popcll(m1 & below)] = tid + 256;
    __syncthreads();

    int tI, tJ;
    decode_tile(t, u, tI, tJ);
    const bool diag = (tI == tJ);

    const float* P = (mat ? T : S) + (size_t)n * CC * LL;
    unsigned short* Dout = (mat ? Dt : Ds) + (((size_t)t * NB + n) << 12);

    // staging: logical rows 0..127 = A rows 0..63 then B rows 64..127 (diag: A only)
    const int srow = w * 32 + (lane >> 1);
    const int half = lane & 1;                 // which 64 B half of the row's 128 B chunk
    const bool stager = diag ? (srow < 64) : true;
    const int ab = srow >> 6, rloc = srow & 63;
    const int gk = (ab ? tJ : tI) * 64 + rloc;
    const int row = s_idx[(gk < np) ? gk : 0];
    const char* rp = (const char*)P + (size_t)row * (LL * 4) + half * 64;

    float4 pre[4];
    float nsum = 0.0f;
    if (stager) {
        #pragma unroll
        for (int i = 0; i < 4; ++i) pre[i] = *(const float4*)(rp + i * 16);
    }

    const int m16 = lane & 15, quad = lane >> 4;
    const int bufB = diag ? 0 : 1;
    const int wrow = w * 16;

    floatx4 acc[4];
    #pragma unroll
    for (int c = 0; c < 4; ++c) { acc[c][0] = 0; acc[c][1] = 0; acc[c][2] = 0; acc[c][3] = 0; }

    for (int kk = 0; kk < 8; ++kk) {
        const int pb = kk & 1;
        if (stager) {
            // safe: chunk kk-2's reads of buf pb drained at barrier kk-1 (lgkmcnt)
            #pragma unroll
            for (int i = 0; i < 4; ++i)
                nsum += pre[i].x * pre[i].x + pre[i].y * pre[i].y +
                        pre[i].z * pre[i].z + pre[i].w * pre[i].w;
            unsigned short* dst = &lds[ab][pb][rloc][half * 16];
            *(uint2*)(dst + 0)  = make_uint2(f2bf2(pre[0].x, pre[0].y), f2bf2(pre[0].z, pre[0].w));
            *(uint2*)(dst + 4)  = make_uint2(f2bf2(pre[1].x, pre[1].y), f2bf2(pre[1].z, pre[1].w));
            *(uint2*)(dst + 8)  = make_uint2(f2bf2(pre[2].x, pre[2].y), f2bf2(pre[2].z, pre[2].w));
            *(uint2*)(dst + 12) = make_uint2(f2bf2(pre[3].x, pre[3].y), f2bf2(pre[3].z, pre[3].w));
        }
        __syncthreads();   // single barrier per chunk
        if (stager && kk < 7) {                // prefetch next chunk during MFMA
            #pragma unroll
            for (int i = 0; i < 4; ++i)
                pre[i] = *(const float4*)(rp + (kk + 1) * 128 + i * 16);
        }
        const short8 a = *(const short8*)&lds[0][pb][wrow + m16][quad * 8];
        #pragma unroll
        for (int c = 0; c < 4; ++c) {
            const short8 b = *(const short8*)&lds[bufB][pb][c * 16 + m16][quad * 8];
            acc[c] = __builtin_amdgcn_mfma_f32_16x16x32_bf16(a, b, acc[c], 0, 0, 0);
        }
    }

    // ---- inline norms: 2 lanes share each staged row ----
    if (stager) {
        const float v = nsum + __shfl_xor(nsum, 1);
        if (half == 0) s_norm[ab][rloc] = v;
    }
    __syncthreads();

    // ---- distances; C/D layout: col=lane&15, row=quad*4+reg ----
    float l0 = 0.0f;
    #pragma unroll
    for (int c = 0; c < 4; ++c) {
        const int colL = c * 16 + m16;
        const int gj = tJ * 64 + colL;
        const float nB = s_norm[bufB][colL];
        #pragma unroll
        for (int r = 0; r < 4; ++r) {
            const int rowL = wrow + quad * 4 + r;
            const int gi = tI * 64 + rowL;
            const float d = sqrtf(fmaxf(s_norm[0][rowL] + nB - 2.0f * acc[c][r], 1e-12f));
            if (gi < np && gj < np && gi != gj) l0 += d;
            Dout[rowL * 64 + colL] = f2h(d);
        }
    }

    #pragma unroll
    for (int o = 32; o; o >>= 1) l0 += __shfl_down(l0, o);
    if (lane == 0) red[w] = l0;
    __syncthreads();
    if (tid == 0) {
        const float wgt = diag ? 1.0f : 2.0f;  // off-diag tiles mirror-counted
        (mat ? sumT : sumS)[t * NB + n] = wgt * (red[0] + red[1] + red[2] + red[3]);
        __threadfence();   // agent release: D tile + sum slot visible device-wide
        s_flag = __hip_atomic_fetch_add(&bcnt[n], 1, __ATOMIC_ACQ_REL, __HIP_MEMORY_SCOPE_AGENT);
    }
    __syncthreads();
    if (s_flag != 2 * ntiles - 1) return;

    // ======== batch finisher (exactly one block per batch) ========
    // The ACQ_REL RMW above acquired at agent scope -> local caches invalidated;
    // all producers' released writes are visible to PLAIN loads from here on.
    float a = 0.0f, b = 0.0f;
    if (lane < ntiles) {                       // ntiles <= 36
        a = sumS[lane * NB + n];
        b = sumT[lane * NB + n];
    }
    #pragma unroll
    for (int o = 32; o; o >>= 1) { a += __shfl_down(a, o); b += __shfl_down(b, o); }
    a = __shfl(a, 0); b = __shfl(b, 0);

    const float cnt = (float)np * (float)(np - 1);
    const float inv_ms = cnt / a;
    const float inv_mt = cnt / b;

    float h = 0.0f;
    for (int tt = 0; tt < ntiles; ++tt) {
        int eI, eJ; decode_tile(tt, u, eI, eJ);
        const float wgt = (eI == eJ) ? 1.0f : 2.0f;
        const size_t slot = ((size_t)tt * NB + n) << 12;
        const uint4* ps = (const uint4*)(Ds + slot);   // 512 uint4 (plain, pipelined)
        const uint4* pt = (const uint4*)(Dt + slot);
        float hl = 0.0f;
        #pragma unroll
        for (int it = 0; it < 2; ++it) {
            const int g = it * 256 + tid;              // uint4 group; 8 entries each
            const uint4 va = ps[g];
            const uint4 vb = pt[g];
            const unsigned aw[4] = { va.x, va.y, va.z, va.w };
            const unsigned bw[4] = { vb.x, vb.y, vb.z, vb.w };
            const int e0 = g * 8;
            #pragma unroll
            for (int k = 0; k < 8; ++k) {
                const int e = e0 + k;
                const int gi = eI * 64 + (e >> 6);
                const int gj = eJ * 64 + (e & 63);
                if (gi < np && gj < np && gi != gj) {
                    const unsigned wa = aw[k >> 1], wb = bw[k >> 1];
                    const float ds = h2f((k & 1) ? (wa >> 16) : (wa & 0xffffu));
                    const float dt = h2f((k & 1) ? (wb >> 16) : (wb & 0xffffu));
                    const float diff = ds * inv_ms - dt * inv_mt;
                    const float ad = fabsf(diff);
                    hl += (ad < 1.0f) ? 0.5f * diff * diff : ad - 0.5f;
                }
            }
        }
        h += wgt * hl;
    }

    #pragma unroll
    for (int o = 32; o; o >>= 1) h += __shfl_down(h, o);
    if (lane == 0) red[w] = h;
    __syncthreads();
    if (tid == 0) {
        hout[n] = (red[0] + red[1] + red[2] + red[3]) / (float)np;
        __threadfence();
        s_flag = __hip_atomic_fetch_add(gcnt, 1, __ATOMIC_ACQ_REL, __HIP_MEMORY_SCOPE_AGENT);
    }
    __syncthreads();
    if (s_flag == NB - 1) {   // globally last batch: sum per-batch results -> out
        if (tid < 64) {
            float v = ld_agent_f32(hout + tid);
            #pragma unroll
            for (int o = 32; o; o >>= 1) v += __shfl_down(v, o);
            if (tid == 0) out[0] = v;
        }
    }
}

extern "C" void kernel_launch(void* const* d_in, const int* in_sizes, int n_in,
                              void* d_out, int out_size, void* d_ws, size_t ws_size,
                              hipStream_t stream) {
    const float* S = (const float*)d_in[0];
    const float* T = (const float*)d_in[1];
    const int* targets = (const int*)d_in[2];
    float* out = (float*)d_out;

    char* p = (char*)d_ws;
    int* bcnt = (int*)p;                          // 64 ints
    int* gcnt = (int*)(p + 256);                  // 1 int
    float* hout = (float*)(p + 512);              // 64 floats
    float* sumS = (float*)(p + 768);              // 36*64 slots
    float* sumT = sumS + 36 * NB;
    p += 768 + (size_t)2 * 36 * NB * 4;
    p = (char*)(((size_t)p + 255) & ~(size_t)255);
    unsigned short* Ds = (unsigned short*)p;  p += (size_t)36 * NB * 4096 * 2;  // 18.9 MB
    unsigned short* Dt = (unsigned short*)p;                                     // 18.9 MB

    hipMemsetAsync(bcnt, 0, 512, stream);         // zero bcnt + gcnt (capture-safe stream op)
    mega_kernel<<<72 * NB, 256, 0, stream>>>(S, T, targets, bcnt, gcnt, hout,
                                             sumS, sumT, Ds, Dt, out);
}

// Round 8
// 128.578 us; speedup vs baseline: 1.9190x; 1.8759x over previous
//
#include <hip/hip_runtime.h>
#include <hip/hip_bf16.h>
#include <hip/hip_fp16.h>
#include <math.h>

#define NB 64
#define CC 512
#define LL 256

typedef __attribute__((ext_vector_type(4))) float floatx4;
typedef __attribute__((ext_vector_type(8))) short short8;

static __device__ __forceinline__ unsigned f2bf2(float x, float y) {
    __hip_bfloat162 h = __float22bfloat162_rn(make_float2(x, y));
    union { __hip_bfloat162 h; unsigned u; } c; c.h = h;
    return c.u;   // low 16 = x, high 16 = y
}
static __device__ __forceinline__ unsigned short f2h(float x) {
    __half h = __float2half_rn(x);
    union { __half h; unsigned short u; } c; c.h = h;
    return c.u;
}
static __device__ __forceinline__ float h2f(unsigned u) {
    union { unsigned short u; __half h; } c; c.u = (unsigned short)u;
    return __half2float(c.h);
}

// decode linear t -> upper-tri (tI,tJ) of a u x u tile grid
static __device__ __forceinline__ bool decode_tile(int t, int u, int& tI, int& tJ) {
    if (t >= (u * (u + 1)) >> 1) return false;
    tI = 0;
    while (t >= u - tI) { t -= u - tI; ++tI; }
    tJ = tI + t;
    return true;
}

// ---------------- K1: 128x128-tile MFMA Gram + distances ----------------
// bx = (t2*2+mat)*64 + n  =>  bx % 8 == n % 8 (XCD-clustered per batch).
// 512 threads / 8 waves per block. 128x128 tiles HALVE staging traffic vs 64x64
// (4 panels/batch/mat instead of 16: the 5x input re-read was dist's wall) and
// double the MFMA:ds_read ratio (16 MFMA : 9 b128 per wave-chunk).
// Per wave: 16 output rows x 128 cols = 8 accumulator fragments.
__global__ __launch_bounds__(512) void dist_kernel(
    const float* __restrict__ S, const float* __restrict__ T,
    const int* __restrict__ targets,
    float* __restrict__ sumS, float* __restrict__ sumT,
    unsigned short* __restrict__ Ds, unsigned short* __restrict__ Dt,
    float* __restrict__ out)
{
    const int bx = blockIdx.x;
    const int n = bx & (NB - 1);
    const int q = bx >> 6;
    const int mat = q & 1, t2 = q >> 1;
    const int tid = threadIdx.x;
    const int w = tid >> 6, lane = tid & 63;

    // bf16 tiles [A/B][dbuf][row][40 halves] = 40 KB (+ idx 2 KB)
    __shared__ __align__(16) unsigned short lds[2][2][128][40];
    __shared__ float s_norm[2][128];
    __shared__ float red[8];
    __shared__ int s_idx[CC];
    __shared__ int s_cnt[8], s_off[8];
    __shared__ int s_np;

    if (bx == 0 && tid == 0) out[0] = 0.0f;   // huber runs strictly after (stream order)

    // ---- in-block ballot compaction: 512 threads = 1 target each ----
    const int* tg = targets + n * CC;
    const bool p0 = tg[tid] != 0;
    const unsigned long long m0 = __ballot(p0);
    if (lane == 0) s_cnt[w] = __popcll(m0);
    __syncthreads();
    if (tid == 0) {
        int a = 0;
        for (int i = 0; i < 8; ++i) { s_off[i] = a; a += s_cnt[i]; }
        s_np = a;
    }
    __syncthreads();
    const int np = s_np;
    if (np < 2) return;
    const int u2 = (np + 127) >> 7;
    int tI2, tJ2;
    if (!decode_tile(t2, u2, tI2, tJ2)) return;
    const bool diag = (tI2 == tJ2);

    const unsigned long long below = (1ull << lane) - 1ull;
    if (p0) s_idx[s_off[w] + __popcll(m0 & below)] = tid;
    __syncthreads();

    const float* P = (mat ? T : S) + (size_t)n * CC * LL;
    unsigned short* Dout = (mat ? Dt : Ds) + (size_t)(t2 * NB + n) * 16384;

    // staging: logical rows 0..255 = A rows 0..127 then B rows 128..255 (diag: A only)
    const int srow = tid >> 1;
    const int half = tid & 1;                  // which 64 B half of the row's 128 B chunk
    const bool stager = diag ? (srow < 128) : true;
    const int ab = srow >> 7, rloc = srow & 127;
    const int gk = (ab ? tJ2 : tI2) * 128 + rloc;
    const int row = s_idx[(gk < np) ? gk : 0];
    const char* rp = (const char*)P + (size_t)row * (LL * 4) + half * 64;

    float4 pre[4];
    float nsum = 0.0f;
    if (stager) {
        #pragma unroll
        for (int i = 0; i < 4; ++i) pre[i] = *(const float4*)(rp + i * 16);
    }

    const int m16 = lane & 15, quad = lane >> 4;
    const int bufB = diag ? 0 : 1;
    const int wrow = w * 16;

    floatx4 acc[8];
    #pragma unroll
    for (int c = 0; c < 8; ++c) { acc[c][0] = 0; acc[c][1] = 0; acc[c][2] = 0; acc[c][3] = 0; }

    for (int kk = 0; kk < 8; ++kk) {
        const int pb = kk & 1;
        if (stager) {
            // safe: chunk kk-2's reads of buf pb drained at barrier kk-1 (lgkmcnt)
            #pragma unroll
            for (int i = 0; i < 4; ++i)
                nsum += pre[i].x * pre[i].x + pre[i].y * pre[i].y +
                        pre[i].z * pre[i].z + pre[i].w * pre[i].w;
            unsigned short* dst = &lds[ab][pb][rloc][half * 16];
            *(uint2*)(dst + 0)  = make_uint2(f2bf2(pre[0].x, pre[0].y), f2bf2(pre[0].z, pre[0].w));
            *(uint2*)(dst + 4)  = make_uint2(f2bf2(pre[1].x, pre[1].y), f2bf2(pre[1].z, pre[1].w));
            *(uint2*)(dst + 8)  = make_uint2(f2bf2(pre[2].x, pre[2].y), f2bf2(pre[2].z, pre[2].w));
            *(uint2*)(dst + 12) = make_uint2(f2bf2(pre[3].x, pre[3].y), f2bf2(pre[3].z, pre[3].w));
        }
        __syncthreads();   // single barrier per chunk
        if (stager && kk < 7) {                // prefetch next chunk during MFMA
            #pragma unroll
            for (int i = 0; i < 4; ++i)
                pre[i] = *(const float4*)(rp + (kk + 1) * 128 + i * 16);
        }
        const short8 a = *(const short8*)&lds[0][pb][wrow + m16][quad * 8];
        #pragma unroll
        for (int c = 0; c < 8; ++c) {
            const short8 b = *(const short8*)&lds[bufB][pb][c * 16 + m16][quad * 8];
            acc[c] = __builtin_amdgcn_mfma_f32_16x16x32_bf16(a, b, acc[c], 0, 0, 0);
        }
    }

    // ---- inline norms: 2 lanes share each staged row ----
    if (stager) {
        const float v = nsum + __shfl_xor(nsum, 1);
        if (half == 0) s_norm[ab][rloc] = v;
    }
    __syncthreads();

    // ---- distances; C/D layout: col=lane&15, row=quad*4+reg ----
    float l0 = 0.0f;
    #pragma unroll
    for (int c = 0; c < 8; ++c) {
        const int colL = c * 16 + m16;
        const int gj = tJ2 * 128 + colL;
        const float nB = s_norm[bufB][colL];
        #pragma unroll
        for (int r = 0; r < 4; ++r) {
            const int rowL = wrow + quad * 4 + r;
            const int gi = tI2 * 128 + rowL;
            const float d = sqrtf(fmaxf(s_norm[0][rowL] + nB - 2.0f * acc[c][r], 1e-12f));
            if (gi < np && gj < np && gi != gj) l0 += d;
            Dout[rowL * 128 + colL] = f2h(d);
        }
    }

    #pragma unroll
    for (int o = 32; o; o >>= 1) l0 += __shfl_down(l0, o);
    if (lane == 0) red[w] = l0;
    __syncthreads();
    if (tid == 0) {
        const float wgt = diag ? 1.0f : 2.0f;  // off-diag tiles mirror-counted
        float s = 0.0f;
        #pragma unroll
        for (int i = 0; i < 8; ++i) s += red[i];
        (mat ? sumT : sumS)[t2 * NB + n] = wgt * s;
    }
}

// ---------------- K2: streaming Huber over fp16 Ds/Dt (64-sub-tile windows) ----------------
// bx = t*64 + n over the 64x64 tile grid (2304 blocks: the parallelism the fan-in
// designs lacked). Reads its 64x64 window out of the 128x128-tile D layout.
__global__ __launch_bounds__(256) void huber_kernel(
    const int* __restrict__ targets,
    const float* __restrict__ sumS, const float* __restrict__ sumT,
    const unsigned short* __restrict__ Ds, const unsigned short* __restrict__ Dt,
    float* __restrict__ out)
{
    const int bx = blockIdx.x;
    const int n = bx & (NB - 1), t = bx >> 6;
    const int tid = threadIdx.x;
    const int w = tid >> 6, lane = tid & 63;

    __shared__ int s_cnt[8];
    __shared__ float red[4];

    const int* tg = targets + n * CC;
    const unsigned long long m0 = __ballot(tg[tid] != 0);
    const unsigned long long m1 = __ballot(tg[tid + 256] != 0);
    if (lane == 0) { s_cnt[w] = __popcll(m0); s_cnt[4 + w] = __popcll(m1); }
    __syncthreads();
    int np = 0;
    #pragma unroll
    for (int i = 0; i < 8; ++i) np += s_cnt[i];   // LDS broadcast, block-uniform

    if (np < 2) return;
    const int u = (np + 63) >> 6;
    int tI, tJ;
    if (!decode_tile(t, u, tI, tJ)) return;

    const int u2 = (np + 127) >> 7;
    const int ntiles2 = (u2 * (u2 + 1)) >> 1;

    // batch sums from unique slots: one wave-reduce per wave (redundant, no barrier)
    float a = 0.0f, b = 0.0f;
    if (lane < ntiles2) { a = sumS[lane * NB + n]; b = sumT[lane * NB + n]; }
    #pragma unroll
    for (int o = 32; o; o >>= 1) { a += __shfl_down(a, o); b += __shfl_down(b, o); }
    a = __shfl(a, 0); b = __shfl(b, 0);

    const float cnt = (float)np * (float)(np - 1);
    const float inv_ms = cnt / a;
    const float inv_mt = cnt / b;

    // 64x64 window inside the 128x128 tile (I2,J2)
    const int I2 = tI >> 1, J2 = tJ >> 1;
    const int t2 = I2 * u2 - ((I2 * (I2 - 1)) >> 1) + (J2 - I2);
    const int rBase = (tI & 1) * 64, cBase = (tJ & 1) * 64;
    const size_t base = (size_t)(t2 * NB + n) * 16384 + (size_t)rBase * 128 + cBase;

    float h = 0.0f;
    #pragma unroll
    for (int it = 0; it < 2; ++it) {
        const int g = it * 256 + tid;              // 8-entry group within the 64x64 window
        const int e0 = g * 8;
        const int r64 = e0 >> 6, c64 = e0 & 63;
        const size_t addr = base + (size_t)r64 * 128 + c64;   // 16B-aligned (c64 mult of 8)
        const uint4 va = *(const uint4*)(Ds + addr);
        const uint4 vb = *(const uint4*)(Dt + addr);
        const unsigned aw[4] = { va.x, va.y, va.z, va.w };
        const unsigned bw[4] = { vb.x, vb.y, vb.z, vb.w };
        const int gi = tI * 64 + r64;
        #pragma unroll
        for (int k = 0; k < 8; ++k) {
            const int gj = tJ * 64 + c64 + k;
            if (gi < np && gj < np && gi != gj) {
                const unsigned wa = aw[k >> 1], wb = bw[k >> 1];
                const float ds = h2f((k & 1) ? (wa >> 16) : (wa & 0xffffu));
                const float dt = h2f((k & 1) ? (wb >> 16) : (wb & 0xffffu));
                const float diff = ds * inv_ms - dt * inv_mt;
                const float ad = fabsf(diff);
                h += (ad < 1.0f) ? 0.5f * diff * diff : ad - 0.5f;
            }
        }
    }

    #pragma unroll
    for (int o = 32; o; o >>= 1) h += __shfl_down(h, o);
    if (lane == 0) red[w] = h;
    __syncthreads();
    if (tid == 0) {
        const float wgt = (tI == tJ) ? 1.0f : 2.0f;
        atomicAdd(out, wgt * (red[0] + red[1] + red[2] + red[3]) / (float)np);
    }
}

extern "C" void kernel_launch(void* const* d_in, const int* in_sizes, int n_in,
                              void* d_out, int out_size, void* d_ws, size_t ws_size,
                              hipStream_t stream) {
    const float* S = (const float*)d_in[0];
    const float* T = (const float*)d_in[1];
    const int* targets = (const int*)d_in[2];
    float* out = (float*)d_out;

    char* p = (char*)d_ws;
    float* sumS = (float*)p;   p += (size_t)10 * NB * 4;   // per-(t2,n) slots
    float* sumT = (float*)p;   p += (size_t)10 * NB * 4;
    p = (char*)(((size_t)p + 255) & ~(size_t)255);
    unsigned short* Ds = (unsigned short*)p;  p += (size_t)10 * NB * 16384 * 2;  // 21 MB
    unsigned short* Dt = (unsigned short*)p;                                      // 21 MB

    // dist: 10 x 128-tile slots x 2 mats x 64 batches; 512 threads (8 waves)
    dist_kernel<<<20 * NB, 512, 0, stream>>>(S, T, targets, sumS, sumT, Ds, Dt, out);
    // huber: 36 x 64-tile slots x 64 batches; 256 threads
    huber_kernel<<<36 * NB, 256, 0, stream>>>(targets, sumS, sumT, Ds, Dt, out);
}

// Round 9
// 122.839 us; speedup vs baseline: 2.0087x; 1.0467x over previous
//
#include <hip/hip_runtime.h>
#include <hip/hip_bf16.h>
#include <hip/hip_fp16.h>
#include <math.h>

#define NB 64
#define CC 512
#define LL 256

typedef __attribute__((ext_vector_type(4))) float floatx4;
typedef __attribute__((ext_vector_type(8))) short short8;

static __device__ __forceinline__ unsigned f2bf2(float x, float y) {
    __hip_bfloat162 h = __float22bfloat162_rn(make_float2(x, y));
    union { __hip_bfloat162 h; unsigned u; } c; c.h = h;
    return c.u;   // low 16 = x, high 16 = y
}
static __device__ __forceinline__ unsigned short f2h(float x) {
    __half h = __float2half_rn(x);
    union { __half h; unsigned short u; } c; c.h = h;
    return c.u;
}
static __device__ __forceinline__ float h2f(unsigned u) {
    union { unsigned short u; __half h; } c; c.u = (unsigned short)u;
    return __half2float(c.h);
}

// decode linear t -> upper-tri (tI,tJ) of a u x u tile grid
static __device__ __forceinline__ bool decode_tile(int t, int u, int& tI, int& tJ) {
    if (t >= (u * (u + 1)) >> 1) return false;
    tI = 0;
    while (t >= u - tI) { t -= u - tI; ++tI; }
    tJ = tI + t;
    return true;
}

// ---------------- K1: compaction-in-block + MFMA Gram + distances ----------------
// bx = (t*2+mat)*64 + n  =>  bx % 8 == n % 8 (XCD-clustered per batch).
// R2-proven structure; only change: inactive blocks exit BEFORE the compaction
// scatter (counts are enough to know np/ntiles), saving a barrier + scatter in
// ~3300 of 4608 blocks.
__global__ __launch_bounds__(256) void dist_kernel(
    const float* __restrict__ S, const float* __restrict__ T,
    const int* __restrict__ targets,
    float* __restrict__ sumS, float* __restrict__ sumT,
    unsigned short* __restrict__ Ds, unsigned short* __restrict__ Dt,
    float* __restrict__ out)
{
    const int bx = blockIdx.x;
    const int n = bx & (NB - 1);
    const int q = bx >> 6;
    const int mat = q & 1, t = q >> 1;
    const int tid = threadIdx.x;
    const int w = tid >> 6, lane = tid & 63;

    // bf16 tiles [A/B][dbuf][row][40 halves] = 20 KB (+ idx 2 KB)
    __shared__ __align__(16) unsigned short lds[2][2][64][40];
    __shared__ float s_norm[2][64];
    __shared__ float red[4];
    __shared__ int s_idx[CC];
    __shared__ int s_cnt[8], s_off[8];
    __shared__ int s_np;

    if (bx == 0 && tid == 0) out[0] = 0.0f;   // huber runs strictly after (stream order)

    // ---- ballot counts ----
    const int* tg = targets + n * CC;
    const bool p0 = tg[tid] != 0;
    const bool p1 = tg[tid + 256] != 0;
    const unsigned long long m0 = __ballot(p0);
    const unsigned long long m1 = __ballot(p1);
    if (lane == 0) { s_cnt[w] = __popcll(m0); s_cnt[4 + w] = __popcll(m1); }
    __syncthreads();
    if (tid == 0) {
        int a = 0;
        for (int i = 0; i < 8; ++i) { s_off[i] = a; a += s_cnt[i]; }
        s_np = a;
    }
    __syncthreads();
    const int np = s_np;

    // early exit BEFORE scatter: counts alone determine activity
    if (np < 2) return;
    int tI, tJ;
    if (!decode_tile(t, (np + 63) >> 6, tI, tJ)) return;
    const bool diag = (tI == tJ);

    // ---- scatter compaction indices (active blocks only) ----
    const unsigned long long below = (1ull << lane) - 1ull;
    if (p0) s_idx[s_off[w] + __popcll(m0 & below)] = tid;
    if (p1) s_idx[s_off[4 + w] + __popcll(m1 & below)] = tid + 256;
    __syncthreads();   // s_idx visible

    const float* P = (mat ? T : S) + (size_t)n * CC * LL;
    unsigned short* Dout = (mat ? Dt : Ds) + (((size_t)t * NB + n) << 12);

    // staging: logical rows 0..127 = A rows 0..63 then B rows 64..127 (diag: A only)
    const int srow = w * 32 + (lane >> 1);
    const int half = lane & 1;                 // which 64 B half of the row's 128 B chunk
    const bool stager = diag ? (srow < 64) : true;
    const int ab = srow >> 6, rloc = srow & 63;
    const int gk = (ab ? tJ : tI) * 64 + rloc;
    const int row = s_idx[(gk < np) ? gk : 0];
    const char* rp = (const char*)P + (size_t)row * (LL * 4) + half * 64;

    float4 pre[4];
    float nsum = 0.0f;
    if (stager) {
        #pragma unroll
        for (int i = 0; i < 4; ++i) pre[i] = *(const float4*)(rp + i * 16);
    }

    const int m16 = lane & 15, quad = lane >> 4;
    const int bufB = diag ? 0 : 1;
    const int wrow = w * 16;

    floatx4 acc[4];
    #pragma unroll
    for (int c = 0; c < 4; ++c) { acc[c][0] = 0; acc[c][1] = 0; acc[c][2] = 0; acc[c][3] = 0; }

    for (int kk = 0; kk < 8; ++kk) {
        const int pb = kk & 1;
        if (stager) {
            // safe: chunk kk-2's reads of buf pb drained at barrier kk-1 (lgkmcnt)
            #pragma unroll
            for (int i = 0; i < 4; ++i)
                nsum += pre[i].x * pre[i].x + pre[i].y * pre[i].y +
                        pre[i].z * pre[i].z + pre[i].w * pre[i].w;
            unsigned short* dst = &lds[ab][pb][rloc][half * 16];
            *(uint2*)(dst + 0)  = make_uint2(f2bf2(pre[0].x, pre[0].y), f2bf2(pre[0].z, pre[0].w));
            *(uint2*)(dst + 4)  = make_uint2(f2bf2(pre[1].x, pre[1].y), f2bf2(pre[1].z, pre[1].w));
            *(uint2*)(dst + 8)  = make_uint2(f2bf2(pre[2].x, pre[2].y), f2bf2(pre[2].z, pre[2].w));
            *(uint2*)(dst + 12) = make_uint2(f2bf2(pre[3].x, pre[3].y), f2bf2(pre[3].z, pre[3].w));
        }
        __syncthreads();   // single barrier per chunk
        if (stager && kk < 7) {                // prefetch next chunk during MFMA
            #pragma unroll
            for (int i = 0; i < 4; ++i)
                pre[i] = *(const float4*)(rp + (kk + 1) * 128 + i * 16);
        }
        const short8 a = *(const short8*)&lds[0][pb][wrow + m16][quad * 8];
        #pragma unroll
        for (int c = 0; c < 4; ++c) {
            const short8 b = *(const short8*)&lds[bufB][pb][c * 16 + m16][quad * 8];
            acc[c] = __builtin_amdgcn_mfma_f32_16x16x32_bf16(a, b, acc[c], 0, 0, 0);
        }
    }

    // ---- inline norms: 2 lanes share each staged row ----
    if (stager) {
        const float v = nsum + __shfl_xor(nsum, 1);
        if (half == 0) s_norm[ab][rloc] = v;
    }
    __syncthreads();

    // ---- distances; C/D layout: col=lane&15, row=quad*4+reg ----
    float l0 = 0.0f;
    #pragma unroll
    for (int c = 0; c < 4; ++c) {
        const int colL = c * 16 + m16;
        const int gj = tJ * 64 + colL;
        const float nB = s_norm[bufB][colL];
        #pragma unroll
        for (int r = 0; r < 4; ++r) {
            const int rowL = wrow + quad * 4 + r;
            const int gi = tI * 64 + rowL;
            const float d = sqrtf(fmaxf(s_norm[0][rowL] + nB - 2.0f * acc[c][r], 1e-12f));
            if (gi < np && gj < np && gi != gj) l0 += d;
            Dout[rowL * 64 + colL] = f2h(d);
        }
    }

    #pragma unroll
    for (int o = 32; o; o >>= 1) l0 += __shfl_down(l0, o);
    if (lane == 0) red[w] = l0;
    __syncthreads();
    if (tid == 0) {
        const float wgt = diag ? 1.0f : 2.0f;  // off-diag tiles mirror-counted
        (mat ? sumT : sumS)[t * NB + n] = wgt * (red[0] + red[1] + red[2] + red[3]);
    }
}

// ---------------- K2: streaming Huber over fp16 Ds/Dt ----------------
// bx = t*64 + n: same XCD as the dist blocks that wrote this tile (L2-hot).
// Counts-only ballot (no scatter needed).
__global__ __launch_bounds__(256) void huber_kernel(
    const int* __restrict__ targets,
    const float* __restrict__ sumS, const float* __restrict__ sumT,
    const unsigned short* __restrict__ Ds, const unsigned short* __restrict__ Dt,
    float* __restrict__ out)
{
    const int bx = blockIdx.x;
    const int n = bx & (NB - 1), t = bx >> 6;
    const int tid = threadIdx.x;
    const int w = tid >> 6, lane = tid & 63;

    __shared__ int s_cnt[8];
    __shared__ float red[4];

    const int* tg = targets + n * CC;
    const unsigned long long m0 = __ballot(tg[tid] != 0);
    const unsigned long long m1 = __ballot(tg[tid + 256] != 0);
    if (lane == 0) { s_cnt[w] = __popcll(m0); s_cnt[4 + w] = __popcll(m1); }
    __syncthreads();
    int np = 0;
    #pragma unroll
    for (int i = 0; i < 8; ++i) np += s_cnt[i];   // LDS broadcast, block-uniform

    if (np < 2) return;
    const int u = (np + 63) >> 6;
    int tI, tJ;
    if (!decode_tile(t, u, tI, tJ)) return;
    const int ntiles = (u * (u + 1)) >> 1;

    // batch sums from unique slots: one wave-reduce per wave (redundant, no barrier)
    float a = 0.0f, b = 0.0f;
    if (lane < ntiles) { a = sumS[lane * NB + n]; b = sumT[lane * NB + n]; }
    #pragma unroll
    for (int o = 32; o; o >>= 1) { a += __shfl_down(a, o); b += __shfl_down(b, o); }
    a = __shfl(a, 0); b = __shfl(b, 0);

    const float cnt = (float)np * (float)(np - 1);
    const float inv_ms = cnt / a;
    const float inv_mt = cnt / b;

    const size_t slot = ((size_t)t * NB + n) << 12;
    const uint4* ps = (const uint4*)(Ds + slot);   // 4096 halves = 512 uint4
    const uint4* pt = (const uint4*)(Dt + slot);

    float h = 0.0f;
    #pragma unroll
    for (int it = 0; it < 2; ++it) {
        const int g = it * 256 + tid;              // uint4 group; 8 entries each
        const uint4 va = ps[g];
        const uint4 vb = pt[g];
        const unsigned aw[4] = { va.x, va.y, va.z, va.w };
        const unsigned bw[4] = { vb.x, vb.y, vb.z, vb.w };
        const int e0 = g * 8;
        #pragma unroll
        for (int k = 0; k < 8; ++k) {
            const int e = e0 + k;
            const int gi = tI * 64 + (e >> 6);
            const int gj = tJ * 64 + (e & 63);
            if (gi < np && gj < np && gi != gj) {
                const unsigned wa = aw[k >> 1], wb = bw[k >> 1];
                const float ds = h2f((k & 1) ? (wa >> 16) : (wa & 0xffffu));
                const float dt = h2f((k & 1) ? (wb >> 16) : (wb & 0xffffu));
                const float diff = ds * inv_ms - dt * inv_mt;
                const float ad = fabsf(diff);
                h += (ad < 1.0f) ? 0.5f * diff * diff : ad - 0.5f;
            }
        }
    }

    #pragma unroll
    for (int o = 32; o; o >>= 1) h += __shfl_down(h, o);
    if (lane == 0) red[w] = h;
    __syncthreads();
    if (tid == 0) {
        const float wgt = (tI == tJ) ? 1.0f : 2.0f;
        atomicAdd(out, wgt * (red[0] + red[1] + red[2] + red[3]) / (float)np);
    }
}

extern "C" void kernel_launch(void* const* d_in, const int* in_sizes, int n_in,
                              void* d_out, int out_size, void* d_ws, size_t ws_size,
                              hipStream_t stream) {
    const float* S = (const float*)d_in[0];
    const float* T = (const float*)d_in[1];
    const int* targets = (const int*)d_in[2];
    float* out = (float*)d_out;

    char* p = (char*)d_ws;
    float* sumS = (float*)p;   p += (size_t)36 * NB * 4;   // per-(t,n) slots
    float* sumT = (float*)p;   p += (size_t)36 * NB * 4;
    p = (char*)(((size_t)p + 255) & ~(size_t)255);
    unsigned short* Ds = (unsigned short*)p;   p += (size_t)36 * NB * 4096 * 2;  // 18.9 MB
    unsigned short* Dt = (unsigned short*)p;                                      // 18.9 MB

    dist_kernel<<<72 * NB, 256, 0, stream>>>(S, T, targets, sumS, sumT, Ds, Dt, out);
    huber_kernel<<<36 * NB, 256, 0, stream>>>(targets, sumS, sumT, Ds, Dt, out);
}